// Round 4
// baseline (4217.122 us; speedup 1.0000x reference)
//
#include <hip/hip_runtime.h>
#include <cstdint>

// Problem constants (from reference)
constexpr int NPTS = 8192;     // N
constexpr int NBATCH = 8;      // B
constexpr int NS = 2048;       // NPOINT
constexpr int NK = 32;         // K neighbors
constexpr int NCH = 64;        // 3 + D(61)
constexpr int NW = 16;         // weightnet out
constexpr int NOC = 128;       // out channels
constexpr int NCAND = 512;     // knn threshold-bin candidate cap
constexpr long long IDX_OUT_OFF = (long long)NBATCH*3*NS + (long long)NBATCH*NOC*NS; // 2146304

// ---------------- K0a: pack xyz+points -> pk[b][n][64] (point-major) ----------------
__global__ __launch_bounds__(256) void pack_kernel(const float* __restrict__ xyz,
    const float* __restrict__ pts, float* __restrict__ pk){
  __shared__ float tile[64][256];
  const int blk = blockIdx.x; const int b = blk >> 5; const int n0 = (blk & 31) * 256;
  const int t = threadIdx.x;
  for (int r = 0; r < 64; ++r) {
    const float* src = (r < 3) ? (xyz + ((size_t)b*3 + r)*NPTS)
                               : (pts + ((size_t)b*61 + (r-3))*NPTS);
    tile[r][t] = src[n0 + t];
  }
  __syncthreads();
  float* dst = pk + ((size_t)b*NPTS + n0 + t)*64;
  #pragma unroll
  for (int c = 0; c < 16; ++c) {
    float4 v = make_float4(tile[4*c][t], tile[4*c+1][t], tile[4*c+2][t], tile[4*c+3][t]);
    *(float4*)(dst + 4*c) = v;
  }
}

// ---------------- K0b: transpose lw[128][1024] -> lwT[1024][128] ----------------
__global__ __launch_bounds__(256) void transpose_lw_kernel(const float* __restrict__ lw,
    float* __restrict__ lwT){
  __shared__ float tile[32][33];
  const int bx = blockIdx.x & 31;   // k-tile (32)
  const int by = blockIdx.x >> 5;   // oc-tile (4)
  const int tx = threadIdx.x & 31, ty0 = threadIdx.x >> 5;
  #pragma unroll
  for (int r = 0; r < 4; ++r){
    int ty = ty0 + r*8;
    tile[ty][tx] = lw[(size_t)(by*32+ty)*1024 + bx*32 + tx];
  }
  __syncthreads();
  #pragma unroll
  for (int r = 0; r < 4; ++r){
    int ty = ty0 + r*8;
    lwT[(size_t)(bx*32+ty)*128 + by*32 + tx] = tile[tx][ty];
  }
}

// ---------------- K1: furthest point sampling (1 block per batch) ----------------
// Exact-match discipline: contract(off), ((dx2+dy2)+dz2), min vs 1e10, argmax first-max.
__global__ __launch_bounds__(1024) void fps_kernel(const float* __restrict__ xyz,
    float* __restrict__ newxyz /*[B][S][3]*/, int* __restrict__ fpsi,
    float* __restrict__ out, int idx_mode){
#pragma clang fp contract(off)
  const int b = blockIdx.x, t = threadIdx.x;
  __shared__ float sx[NPTS], sy[NPTS], sz[NPTS];
  __shared__ float rv[16]; __shared__ int ri[16];
  __shared__ int swin;
  const float* xb = xyz + (size_t)b*3*NPTS;
  float px[8], py[8], pz[8], md[8];
  #pragma unroll
  for (int j = 0; j < 8; ++j){
    int n = t + j*1024;
    float x = xb[n], y = xb[NPTS+n], z = xb[2*NPTS+n];
    px[j]=x; py[j]=y; pz[j]=z; sx[n]=x; sy[n]=y; sz[n]=z;
    md[j]=1e10f;
  }
  __syncthreads();
  int last = 0;
  for (int s = 0;; ++s){
    if (t == 0){
      float cx=sx[last], cy=sy[last], cz=sz[last];
      fpsi[b*NS+s]=last;
      size_t o = ((size_t)b*NS+s)*3;
      newxyz[o]=cx; newxyz[o+1]=cy; newxyz[o+2]=cz;
      out[(size_t)b*3*NS + s]        = cx;
      out[(size_t)b*3*NS + NS + s]   = cy;
      out[(size_t)b*3*NS + 2*NS + s] = cz;
      if (idx_mode == 0) out[IDX_OUT_OFF + (size_t)b*NS + s] = (float)last;
      else ((long long*)(out + IDX_OUT_OFF))[(size_t)b*NS + s] = (long long)last;
    }
    if (s == NS-1) break;
    float qx=sx[last], qy=sy[last], qz=sz[last];
    float bv = -1.0f; int bi = 0x7fffffff;
    #pragma unroll
    for (int j = 0; j < 8; ++j){
      float dx=px[j]-qx, dy=py[j]-qy, dz=pz[j]-qz;
      float d = (dx*dx + dy*dy) + dz*dz;
      float m = fminf(md[j], d);
      md[j] = m;
      if (m > bv){ bv = m; bi = t + j*1024; }   // ascending j => smallest idx on tie
    }
    #pragma unroll
    for (int off = 32; off; off >>= 1){
      float ov = __shfl_xor(bv, off); int oi = __shfl_xor(bi, off);
      if (ov > bv || (ov == bv && oi < bi)){ bv = ov; bi = oi; }
    }
    if ((t & 63) == 0){ rv[t>>6] = bv; ri[t>>6] = bi; }
    __syncthreads();
    if (t < 64){
      float v = (t < 16) ? rv[t] : -1.0f;
      int  i = (t < 16) ? ri[t] : 0x7fffffff;
      #pragma unroll
      for (int off = 8; off; off >>= 1){
        float ov = __shfl_xor(v, off); int oi = __shfl_xor(i, off);
        if (ov > v || (ov == v && oi < i)){ v = ov; i = oi; }
      }
      if (t == 0) swin = i;
    }
    __syncthreads();
    last = swin;
  }
}

// ---------------- K2: KNN via per-query histogram select (1 block per query) ----------------
// Distance formula mimics reference: d = (|q|^2 + |p|^2) - 2*((qx*px+qy*py)+qz*pz),
// mul/add (no fma contraction) to track XLA's emission; can be slightly negative.
__global__ __launch_bounds__(256) void knn_kernel(const float* __restrict__ xyz,
    const float* __restrict__ nxyz /*[B][S][3]*/, int* __restrict__ knn_out){
#pragma clang fp contract(off)
  const int q = blockIdx.x; const int b = q >> 11;
  const int t = threadIdx.x;
  __shared__ float dist[NPTS];
  __shared__ unsigned hist[4096];
  __shared__ unsigned scnt[256];
  __shared__ int s_bin, s_below;
  __shared__ unsigned cnt_sure, cnt_cand;
  __shared__ float cd[NCAND]; __shared__ int cidx[NCAND];
  const float* xb = xyz + (size_t)b*3*NPTS;
  const float qx = nxyz[(size_t)q*3+0], qy = nxyz[(size_t)q*3+1], qz = nxyz[(size_t)q*3+2];
  const float sqq = (qx*qx + qy*qy) + qz*qz;
  #pragma unroll
  for (int j = 0; j < 16; ++j) hist[t + 256*j] = 0u;
  if (t == 0){ cnt_sure = 0u; cnt_cand = 0u; }
  __syncthreads();
  #pragma unroll
  for (int j = 0; j < 32; ++j){
    int n = t + 256*j;
    float x = xb[n], y = xb[NPTS+n], z = xb[2*NPTS+n];
    float sqn = (x*x + y*y) + z*z;
    float dot = (qx*x + qy*y) + qz*z;
    float d = (sqq + sqn) - 2.0f*dot;
    dist[n] = d;
    unsigned ub = __float_as_uint(d);
    ub = (ub & 0x80000000u) ? ~ub : (ub | 0x80000000u);  // monotonic float->uint
    atomicAdd(&hist[ub >> 20], 1u);
  }
  __syncthreads();
  unsigned ps = 0;
  #pragma unroll
  for (int j = 0; j < 16; ++j) ps += hist[t*16 + j];
  scnt[t] = ps;
  __syncthreads();
  if (t < 64){
    unsigned v4 = scnt[4*t] + scnt[4*t+1] + scnt[4*t+2] + scnt[4*t+3];
    unsigned cum = v4;
    #pragma unroll
    for (int o = 1; o < 64; o <<= 1){
      unsigned p = __shfl_up(cum, o);
      if (t >= o) cum += p;
    }
    unsigned long long mask = __ballot(cum >= 32u);
    int L = __ffsll(mask) - 1;
    if (t == L){
      unsigned below = cum - v4;
      int bin = -1;
      for (int i = 4*L; i < 4*L+4; ++i){
        if (below + scnt[i] >= 32u){
          for (int k = 16*i;; ++k){
            if (below + hist[k] >= 32u){ bin = k; break; }
            below += hist[k];
          }
          break;
        }
        below += scnt[i];
      }
      s_bin = bin; s_below = (int)below;
    }
  }
  __syncthreads();
  const int Bb = s_bin, below = s_below, m = 32 - below;
  int* outp = knn_out + (size_t)q*NK;
  #pragma unroll
  for (int j = 0; j < 32; ++j){
    int n = t + 256*j;
    unsigned ub = __float_as_uint(dist[n]);
    ub = (ub & 0x80000000u) ? ~ub : (ub | 0x80000000u);
    unsigned bin = ub >> 20;
    if (bin < (unsigned)Bb){
      unsigned p = atomicAdd(&cnt_sure, 1u);
      outp[p] = n;
    } else if (bin == (unsigned)Bb){
      unsigned p = atomicAdd(&cnt_cand, 1u);
      if (p < (unsigned)NCAND){ cd[p] = dist[n]; cidx[p] = n; }
    }
  }
  __syncthreads();
  int c = (int)cnt_cand; if (c > NCAND) c = NCAND;
  if (t < c){
    float myd = cd[t]; int myi = cidx[t];
    int r = 0;
    for (int j = 0; j < c; ++j){
      float dj = cd[j]; int ij = cidx[j];
      if (dj < myd || (dj == myd && ij < myi)) r++;
    }
    if (r < m) outp[below + r] = myi;
  }
  // candidate entries 256..c-1 (c can exceed blockDim)
  for (int base = 256; base < c; base += 256){
    int idx = base + t;
    if (idx < c){
      float myd = cd[idx]; int myi = cidx[idx];
      int r = 0;
      for (int j = 0; j < c; ++j){
        float dj = cd[j]; int ij = cidx[j];
        if (dj < myd || (dj == myd && ij < myi)) r++;
      }
      if (r < m) outp[below + r] = myi;
    }
  }
}

// ---------------- K3: gather + WeightNet + aggregate -> agg[q][1024] ----------------
__global__ __launch_bounds__(256) void group_agg_kernel(const float* __restrict__ pk,
    const float* __restrict__ nxyz, const int* __restrict__ knn_in,
    const float* __restrict__ w1, const float* __restrict__ b1,
    const float* __restrict__ w2, const float* __restrict__ b2,
    const float* __restrict__ w3, const float* __restrict__ b3,
    float* __restrict__ agg){
  const int t = threadIdx.x;
  __shared__ float np[32][65];
  __shared__ float h1[32][9];
  __shared__ float h2[32][9];
  __shared__ float wt[32][17];
  __shared__ int sidx[32];
  const int kg = t >> 3, c0 = (t & 7) * 8;   // gather: (k, 8 channels)
  const int ko = t >> 3, oo = t & 7;         // layers 1/2: (k, out)
  const int kw = t >> 4, wo = t & 15;        // layer 3: (k, w) ×2
  const int ca = t >> 2, wa = (t & 3) * 4;   // agg: (c, 4 w)
  for (int qq = 0; qq < 8; ++qq){
    const int q = blockIdx.x*8 + qq;
    const int b = q >> 11;
    if (t < 32) sidx[t] = knn_in[(size_t)q*NK + t];
    __syncthreads();
    const float qx = nxyz[(size_t)q*3+0], qy = nxyz[(size_t)q*3+1], qz = nxyz[(size_t)q*3+2];
    {
      const float* src = pk + ((size_t)b*NPTS + sidx[kg])*64 + c0;
      float4 v0 = *(const float4*)src;
      float4 v1 = *(const float4*)(src + 4);
      if (c0 == 0){ v0.x -= qx; v0.y -= qy; v0.z -= qz; }
      np[kg][c0+0]=v0.x; np[kg][c0+1]=v0.y; np[kg][c0+2]=v0.z; np[kg][c0+3]=v0.w;
      np[kg][c0+4]=v1.x; np[kg][c0+5]=v1.y; np[kg][c0+6]=v1.z; np[kg][c0+7]=v1.w;
    }
    __syncthreads();
    h1[ko][oo] = fmaxf(w1[oo*3+0]*np[ko][0] + w1[oo*3+1]*np[ko][1] + w1[oo*3+2]*np[ko][2] + b1[oo], 0.f);
    __syncthreads();
    {
      float a = b2[oo];
      #pragma unroll
      for (int j = 0; j < 8; ++j) a = fmaf(w2[oo*8+j], h1[ko][j], a);
      h2[ko][oo] = fmaxf(a, 0.f);
    }
    __syncthreads();
    {
      float a = b3[wo], a2 = b3[wo];
      #pragma unroll
      for (int j = 0; j < 8; ++j){
        a  = fmaf(w3[wo*8+j], h2[kw][j],    a);
        a2 = fmaf(w3[wo*8+j], h2[kw+16][j], a2);
      }
      wt[kw][wo]    = fmaxf(a, 0.f);
      wt[kw+16][wo] = fmaxf(a2, 0.f);
    }
    __syncthreads();
    {
      float a0=0.f, a1=0.f, a2=0.f, a3=0.f;
      #pragma unroll
      for (int k = 0; k < 32; ++k){
        float a = np[k][ca];
        a0 = fmaf(a, wt[k][wa+0], a0);
        a1 = fmaf(a, wt[k][wa+1], a1);
        a2 = fmaf(a, wt[k][wa+2], a2);
        a3 = fmaf(a, wt[k][wa+3], a3);
      }
      *(float4*)(agg + (size_t)q*1024 + ca*16 + wa) = make_float4(a0,a1,a2,a3);
    }
    __syncthreads();
  }
}

// ---------------- K4: out = leaky(agg @ lwT + lb), transposed write ----------------
__global__ __launch_bounds__(256) void out_gemm_kernel(const float* __restrict__ agg,
    const float* __restrict__ lwT, const float* __restrict__ lb, float* __restrict__ out){
  __shared__ float At[32][68];   // [k][m], padded
  const int t = threadIdx.x;
  const int m0 = blockIdx.x * 64;
  const int tm = t >> 4, tn = t & 15;      // thread tile: 4 m × 8 oc
  const int sr = t >> 2, sq = (t & 3) * 2; // staging: row, float4-quad pair
  float acc[4][8];
  #pragma unroll
  for (int i = 0; i < 4; ++i)
    #pragma unroll
    for (int j = 0; j < 8; ++j) acc[i][j] = 0.f;
  for (int kt = 0; kt < 32; ++kt){
    const float4* srcA = (const float4*)(agg + ((size_t)(m0+sr))*1024 + (size_t)kt*32);
    float4 a0 = srcA[sq], a1 = srcA[sq+1];
    __syncthreads();
    At[sq*4+0][sr]=a0.x; At[sq*4+1][sr]=a0.y; At[sq*4+2][sr]=a0.z; At[sq*4+3][sr]=a0.w;
    At[sq*4+4][sr]=a1.x; At[sq*4+5][sr]=a1.y; At[sq*4+6][sr]=a1.z; At[sq*4+7][sr]=a1.w;
    __syncthreads();
    const float* bbase = lwT + (size_t)kt*32*128 + tn*8;
    #pragma unroll
    for (int k = 0; k < 32; ++k){
      float4 av = *(const float4*)&At[k][tm*4];
      float4 b0 = *(const float4*)(bbase + k*128);
      float4 b1 = *(const float4*)(bbase + k*128 + 4);
      float a_[4] = {av.x, av.y, av.z, av.w};
      float b_[8] = {b0.x,b0.y,b0.z,b0.w,b1.x,b1.y,b1.z,b1.w};
      #pragma unroll
      for (int i = 0; i < 4; ++i)
        #pragma unroll
        for (int j = 0; j < 8; ++j) acc[i][j] = fmaf(a_[i], b_[j], acc[i][j]);
    }
  }
  #pragma unroll
  for (int i = 0; i < 4; ++i){
    const int m = m0 + tm*4 + i;
    const int b = m >> 11, s = m & 2047;
    #pragma unroll
    for (int j = 0; j < 8; ++j){
      const int oc = tn*8 + j;
      float v = acc[i][j] + lb[oc];
      v = (v >= 0.f) ? v : 0.1f*v;
      out[((size_t)b*NOC + oc)*NS + s] = v;
    }
  }
}

// ---------------- host ----------------
extern "C" void kernel_launch(void* const* d_in, const int* in_sizes, int n_in,
                              void* d_out, int out_size, void* d_ws, size_t ws_size,
                              hipStream_t stream){
  const float* xyz = (const float*)d_in[0];
  const float* pts = (const float*)d_in[1];
  const float* w1  = (const float*)d_in[2];
  const float* b1  = (const float*)d_in[3];
  const float* w2  = (const float*)d_in[4];
  const float* b2  = (const float*)d_in[5];
  const float* w3  = (const float*)d_in[6];
  const float* b3  = (const float*)d_in[7];
  const float* lw  = (const float*)d_in[8];
  const float* lb  = (const float*)d_in[9];
  float* out = (float*)d_out;
  float* ws  = (float*)d_ws;
  // ws layout (floats): needs ~86.8 MB total
  float* pk   = ws;                    // 4,194,304  : packed [B][N][64]
  float* nxyz = ws + 4194304;          //    49,152  : new_xyz [B][S][3]
  int*   fpsi = (int*)(ws + 4243456);  //    16,384  : fps idx
  int*   knn_ = (int*)(ws + 4259840);  //   524,288  : knn idx [B][S][32]
  float* lwT  = ws + 4784128;          //   131,072  : lw transposed [1024][128]
  float* agg  = ws + 4915200;          // 16,777,216 : agg [B*S][1024]
  // fps_idx output convention: float (out_size==2162688) vs raw int64 (2179072)
  const int idx_mode = (out_size >= 2179072) ? 1 : 0;

  pack_kernel<<<dim3(256), dim3(256), 0, stream>>>(xyz, pts, pk);
  transpose_lw_kernel<<<dim3(128), dim3(256), 0, stream>>>(lw, lwT);
  fps_kernel<<<dim3(NBATCH), dim3(1024), 0, stream>>>(xyz, nxyz, fpsi, out, idx_mode);
  knn_kernel<<<dim3(NBATCH*NS), dim3(256), 0, stream>>>(xyz, nxyz, knn_);
  group_agg_kernel<<<dim3(2048), dim3(256), 0, stream>>>(pk, nxyz, knn_,
      w1, b1, w2, b2, w3, b3, agg);
  out_gemm_kernel<<<dim3(256), dim3(256), 0, stream>>>(agg, lwT, lb, out + NBATCH*3*NS);
}

// Round 12
// 3478.788 us; speedup vs baseline: 1.2122x; 1.2122x over previous
//
#include <hip/hip_runtime.h>
#include <cstdint>

// Problem constants (from reference)
constexpr int NPTS = 8192;     // N
constexpr int NBATCH = 8;      // B
constexpr int NS = 2048;       // NPOINT
constexpr int NK = 32;         // K neighbors
constexpr int NCH = 64;        // 3 + D(61)
constexpr int NW = 16;         // weightnet out
constexpr int NOC = 128;       // out channels
constexpr int NCAND = 512;     // knn threshold-bin candidate cap
constexpr long long IDX_OUT_OFF = (long long)NBATCH*3*NS + (long long)NBATCH*NOC*NS; // 2146304

// ---------------- K0a: pack xyz+points -> pk[b][n][64] (point-major) ----------------
__global__ __launch_bounds__(256) void pack_kernel(const float* __restrict__ xyz,
    const float* __restrict__ pts, float* __restrict__ pk){
  __shared__ float tile[64][256];
  const int blk = blockIdx.x; const int b = blk >> 5; const int n0 = (blk & 31) * 256;
  const int t = threadIdx.x;
  for (int r = 0; r < 64; ++r) {
    const float* src = (r < 3) ? (xyz + ((size_t)b*3 + r)*NPTS)
                               : (pts + ((size_t)b*61 + (r-3))*NPTS);
    tile[r][t] = src[n0 + t];
  }
  __syncthreads();
  float* dst = pk + ((size_t)b*NPTS + n0 + t)*64;
  #pragma unroll
  for (int c = 0; c < 16; ++c) {
    float4 v = make_float4(tile[4*c][t], tile[4*c+1][t], tile[4*c+2][t], tile[4*c+3][t]);
    *(float4*)(dst + 4*c) = v;
  }
}

// ---------------- K0b: transpose lw[128][1024] -> lwT[1024][128] ----------------
__global__ __launch_bounds__(256) void transpose_lw_kernel(const float* __restrict__ lw,
    float* __restrict__ lwT){
  __shared__ float tile[32][33];
  const int bx = blockIdx.x & 31;   // k-tile (32)
  const int by = blockIdx.x >> 5;   // oc-tile (4)
  const int tx = threadIdx.x & 31, ty0 = threadIdx.x >> 5;
  #pragma unroll
  for (int r = 0; r < 4; ++r){
    int ty = ty0 + r*8;
    tile[ty][tx] = lw[(size_t)(by*32+ty)*1024 + bx*32 + tx];
  }
  __syncthreads();
  #pragma unroll
  for (int r = 0; r < 4; ++r){
    int ty = ty0 + r*8;
    lwT[(size_t)(bx*32+ty)*128 + by*32 + tx] = tile[tx][ty];
  }
}

// ---------------- K1: furthest point sampling (1 block per batch) ----------------
// Two-barrier, no serial wave-0 stage, no global stores in the loop.
// Per-wave u64 shfl-xor max reduce -> lane0 LDS atomicMax into double-buffered slot.
// Packed key = (f32bits(maxmin) << 32) | ~idx  (dists >= 0 so float bits are
// monotonic; ~idx => smallest index wins ties, matching jnp.argmax first-max).
// Race-freedom: zero of slot[(s+1)&1] sits between B1 and B2; its next atomicMax
// (step s+1) is after B2, its previous read (step s-1) was before B2(s-1)+B1(s).
// Update numerics bit-identical to verified r4 kernel: contract(off),
// ((dx2+dy2)+dz2), fminf vs 1e10 init, per-thread strict > over ascending j.
__global__ __launch_bounds__(1024) void fps_kernel(const float* __restrict__ xyz,
    float* __restrict__ newxyz /*[B][S][3]*/, float* __restrict__ out, int idx_mode){
#pragma clang fp contract(off)
  const int b = blockIdx.x, t = threadIdx.x;
  __shared__ float4 spt[NPTS];               // 128 KB: (x,y,z,0) per point
  __shared__ int shist[NS];                  // 8 KB: chosen index per step
  __shared__ unsigned long long slot[2];
  const float* xb = xyz + (size_t)b*3*NPTS;
  float px[8], py[8], pz[8], md[8];
  #pragma unroll
  for (int j = 0; j < 8; ++j){
    int n = t + j*1024;
    float x = xb[n], y = xb[NPTS+n], z = xb[2*NPTS+n];
    px[j]=x; py[j]=y; pz[j]=z;
    spt[n] = make_float4(x, y, z, 0.f);
    md[j] = 1e10f;
  }
  if (t == 0){ slot[0] = 0ull; slot[1] = 0ull; }
  __syncthreads();
  int last = 0;
  float4 c0 = spt[0];
  float qx = c0.x, qy = c0.y, qz = c0.z;
  for (int s = 0; s < NS-1; ++s){
    if (t == 0) shist[s] = last;
    float bv = -1.0f; int bi = 0;
    #pragma unroll
    for (int j = 0; j < 8; ++j){
      float dx=px[j]-qx, dy=py[j]-qy, dz=pz[j]-qz;
      float d = (dx*dx + dy*dy) + dz*dz;
      float m = fminf(md[j], d);
      md[j] = m;
      if (m > bv){ bv = m; bi = t + j*1024; }   // ascending j => smallest idx on tie
    }
    unsigned long long pk =
        ((unsigned long long)__float_as_uint(bv) << 32) | (unsigned)(~bi);
    #pragma unroll
    for (int off = 32; off; off >>= 1){
      unsigned long long o2 = __shfl_xor(pk, off);
      if (o2 > pk) pk = o2;
    }
    if ((t & 63) == 0) atomicMax(&slot[s & 1], pk);
    __syncthreads();                            // B1: all atomicMaxes visible
    unsigned long long win = slot[s & 1];
    last = (int)(~(unsigned)win);
    float4 cc = spt[last];                      // broadcast b128
    qx = cc.x; qy = cc.y; qz = cc.z;
    if (t == 0) slot[(s + 1) & 1] = 0ull;
    __syncthreads();                            // B2: zero visible before next use
  }
  if (t == 0) shist[NS-1] = last;
  __syncthreads();
  // epilogue: write all outputs from shist/spt (2 rounds of 1024 threads)
  #pragma unroll
  for (int r = 0; r < 2; ++r){
    int s = t + r*1024;
    int idx = shist[s];
    float4 c = spt[idx];
    size_t o = ((size_t)b*NS+s)*3;
    newxyz[o]=c.x; newxyz[o+1]=c.y; newxyz[o+2]=c.z;
    out[(size_t)b*3*NS + s]        = c.x;
    out[(size_t)b*3*NS + NS + s]   = c.y;
    out[(size_t)b*3*NS + 2*NS + s] = c.z;
    if (idx_mode == 0) out[IDX_OUT_OFF + (size_t)b*NS + s] = (float)idx;
    else ((long long*)(out + IDX_OUT_OFF))[(size_t)b*NS + s] = (long long)idx;
  }
}

// ---------------- K2: KNN via per-query histogram select (1 block per query) ----------------
// Distance formula mimics reference: d = (|q|^2 + |p|^2) - 2*((qx*px+qy*py)+qz*pz),
// mul/add (no fma contraction) to track XLA's emission; can be slightly negative.
__global__ __launch_bounds__(256) void knn_kernel(const float* __restrict__ xyz,
    const float* __restrict__ nxyz /*[B][S][3]*/, int* __restrict__ knn_out){
#pragma clang fp contract(off)
  const int q = blockIdx.x; const int b = q >> 11;
  const int t = threadIdx.x;
  __shared__ float dist[NPTS];
  __shared__ unsigned hist[4096];
  __shared__ unsigned scnt[256];
  __shared__ int s_bin, s_below;
  __shared__ unsigned cnt_sure, cnt_cand;
  __shared__ float cd[NCAND]; __shared__ int cidx[NCAND];
  const float* xb = xyz + (size_t)b*3*NPTS;
  const float qx = nxyz[(size_t)q*3+0], qy = nxyz[(size_t)q*3+1], qz = nxyz[(size_t)q*3+2];
  const float sqq = (qx*qx + qy*qy) + qz*qz;
  #pragma unroll
  for (int j = 0; j < 16; ++j) hist[t + 256*j] = 0u;
  if (t == 0){ cnt_sure = 0u; cnt_cand = 0u; }
  __syncthreads();
  #pragma unroll
  for (int j = 0; j < 32; ++j){
    int n = t + 256*j;
    float x = xb[n], y = xb[NPTS+n], z = xb[2*NPTS+n];
    float sqn = (x*x + y*y) + z*z;
    float dot = (qx*x + qy*y) + qz*z;
    float d = (sqq + sqn) - 2.0f*dot;
    dist[n] = d;
    unsigned ub = __float_as_uint(d);
    ub = (ub & 0x80000000u) ? ~ub : (ub | 0x80000000u);  // monotonic float->uint
    atomicAdd(&hist[ub >> 20], 1u);
  }
  __syncthreads();
  unsigned ps = 0;
  #pragma unroll
  for (int j = 0; j < 16; ++j) ps += hist[t*16 + j];
  scnt[t] = ps;
  __syncthreads();
  if (t < 64){
    unsigned v4 = scnt[4*t] + scnt[4*t+1] + scnt[4*t+2] + scnt[4*t+3];
    unsigned cum = v4;
    #pragma unroll
    for (int o = 1; o < 64; o <<= 1){
      unsigned p = __shfl_up(cum, o);
      if (t >= o) cum += p;
    }
    unsigned long long mask = __ballot(cum >= 32u);
    int L = __ffsll(mask) - 1;
    if (t == L){
      unsigned below = cum - v4;
      int bin = -1;
      for (int i = 4*L; i < 4*L+4; ++i){
        if (below + scnt[i] >= 32u){
          for (int k = 16*i;; ++k){
            if (below + hist[k] >= 32u){ bin = k; break; }
            below += hist[k];
          }
          break;
        }
        below += scnt[i];
      }
      s_bin = bin; s_below = (int)below;
    }
  }
  __syncthreads();
  const int Bb = s_bin, below = s_below, m = 32 - below;
  int* outp = knn_out + (size_t)q*NK;
  #pragma unroll
  for (int j = 0; j < 32; ++j){
    int n = t + 256*j;
    unsigned ub = __float_as_uint(dist[n]);
    ub = (ub & 0x80000000u) ? ~ub : (ub | 0x80000000u);
    unsigned bin = ub >> 20;
    if (bin < (unsigned)Bb){
      unsigned p = atomicAdd(&cnt_sure, 1u);
      outp[p] = n;
    } else if (bin == (unsigned)Bb){
      unsigned p = atomicAdd(&cnt_cand, 1u);
      if (p < (unsigned)NCAND){ cd[p] = dist[n]; cidx[p] = n; }
    }
  }
  __syncthreads();
  int c = (int)cnt_cand; if (c > NCAND) c = NCAND;
  if (t < c){
    float myd = cd[t]; int myi = cidx[t];
    int r = 0;
    for (int j = 0; j < c; ++j){
      float dj = cd[j]; int ij = cidx[j];
      if (dj < myd || (dj == myd && ij < myi)) r++;
    }
    if (r < m) outp[below + r] = myi;
  }
  // candidate entries 256..c-1 (c can exceed blockDim)
  for (int base = 256; base < c; base += 256){
    int idx = base + t;
    if (idx < c){
      float myd = cd[idx]; int myi = cidx[idx];
      int r = 0;
      for (int j = 0; j < c; ++j){
        float dj = cd[j]; int ij = cidx[j];
        if (dj < myd || (dj == myd && ij < myi)) r++;
      }
      if (r < m) outp[below + r] = myi;
    }
  }
}

// ---------------- K3: gather + WeightNet + aggregate -> agg[q][1024] ----------------
__global__ __launch_bounds__(256) void group_agg_kernel(const float* __restrict__ pk,
    const float* __restrict__ nxyz, const int* __restrict__ knn_in,
    const float* __restrict__ w1, const float* __restrict__ b1,
    const float* __restrict__ w2, const float* __restrict__ b2,
    const float* __restrict__ w3, const float* __restrict__ b3,
    float* __restrict__ agg){
  const int t = threadIdx.x;
  __shared__ float np[32][65];
  __shared__ float h1[32][9];
  __shared__ float h2[32][9];
  __shared__ float wt[32][17];
  __shared__ int sidx[32];
  const int kg = t >> 3, c0 = (t & 7) * 8;   // gather: (k, 8 channels)
  const int ko = t >> 3, oo = t & 7;         // layers 1/2: (k, out)
  const int kw = t >> 4, wo = t & 15;        // layer 3: (k, w) ×2
  const int ca = t >> 2, wa = (t & 3) * 4;   // agg: (c, 4 w)
  for (int qq = 0; qq < 8; ++qq){
    const int q = blockIdx.x*8 + qq;
    const int b = q >> 11;
    if (t < 32) sidx[t] = knn_in[(size_t)q*NK + t];
    __syncthreads();
    const float qx = nxyz[(size_t)q*3+0], qy = nxyz[(size_t)q*3+1], qz = nxyz[(size_t)q*3+2];
    {
      const float* src = pk + ((size_t)b*NPTS + sidx[kg])*64 + c0;
      float4 v0 = *(const float4*)src;
      float4 v1 = *(const float4*)(src + 4);
      if (c0 == 0){ v0.x -= qx; v0.y -= qy; v0.z -= qz; }
      np[kg][c0+0]=v0.x; np[kg][c0+1]=v0.y; np[kg][c0+2]=v0.z; np[kg][c0+3]=v0.w;
      np[kg][c0+4]=v1.x; np[kg][c0+5]=v1.y; np[kg][c0+6]=v1.z; np[kg][c0+7]=v1.w;
    }
    __syncthreads();
    h1[ko][oo] = fmaxf(w1[oo*3+0]*np[ko][0] + w1[oo*3+1]*np[ko][1] + w1[oo*3+2]*np[ko][2] + b1[oo], 0.f);
    __syncthreads();
    {
      float a = b2[oo];
      #pragma unroll
      for (int j = 0; j < 8; ++j) a = fmaf(w2[oo*8+j], h1[ko][j], a);
      h2[ko][oo] = fmaxf(a, 0.f);
    }
    __syncthreads();
    {
      float a = b3[wo], a2 = b3[wo];
      #pragma unroll
      for (int j = 0; j < 8; ++j){
        a  = fmaf(w3[wo*8+j], h2[kw][j],    a);
        a2 = fmaf(w3[wo*8+j], h2[kw+16][j], a2);
      }
      wt[kw][wo]    = fmaxf(a, 0.f);
      wt[kw+16][wo] = fmaxf(a2, 0.f);
    }
    __syncthreads();
    {
      float a0=0.f, a1=0.f, a2=0.f, a3=0.f;
      #pragma unroll
      for (int k = 0; k < 32; ++k){
        float a = np[k][ca];
        a0 = fmaf(a, wt[k][wa+0], a0);
        a1 = fmaf(a, wt[k][wa+1], a1);
        a2 = fmaf(a, wt[k][wa+2], a2);
        a3 = fmaf(a, wt[k][wa+3], a3);
      }
      *(float4*)(agg + (size_t)q*1024 + ca*16 + wa) = make_float4(a0,a1,a2,a3);
    }
    __syncthreads();
  }
}

// ---------------- K4: out = leaky(agg @ lwT + lb), transposed write ----------------
__global__ __launch_bounds__(256) void out_gemm_kernel(const float* __restrict__ agg,
    const float* __restrict__ lwT, const float* __restrict__ lb, float* __restrict__ out){
  __shared__ float At[32][68];   // [k][m], padded
  const int t = threadIdx.x;
  const int m0 = blockIdx.x * 64;
  const int tm = t >> 4, tn = t & 15;      // thread tile: 4 m × 8 oc
  const int sr = t >> 2, sq = (t & 3) * 2; // staging: row, float4-quad pair
  float acc[4][8];
  #pragma unroll
  for (int i = 0; i < 4; ++i)
    #pragma unroll
    for (int j = 0; j < 8; ++j) acc[i][j] = 0.f;
  for (int kt = 0; kt < 32; ++kt){
    const float4* srcA = (const float4*)(agg + ((size_t)(m0+sr))*1024 + (size_t)kt*32);
    float4 a0 = srcA[sq], a1 = srcA[sq+1];
    __syncthreads();
    At[sq*4+0][sr]=a0.x; At[sq*4+1][sr]=a0.y; At[sq*4+2][sr]=a0.z; At[sq*4+3][sr]=a0.w;
    At[sq*4+4][sr]=a1.x; At[sq*4+5][sr]=a1.y; At[sq*4+6][sr]=a1.z; At[sq*4+7][sr]=a1.w;
    __syncthreads();
    const float* bbase = lwT + (size_t)kt*32*128 + tn*8;
    #pragma unroll
    for (int k = 0; k < 32; ++k){
      float4 av = *(const float4*)&At[k][tm*4];
      float4 b0 = *(const float4*)(bbase + k*128);
      float4 b1 = *(const float4*)(bbase + k*128 + 4);
      float a_[4] = {av.x, av.y, av.z, av.w};
      float b_[8] = {b0.x,b0.y,b0.z,b0.w,b1.x,b1.y,b1.z,b1.w};
      #pragma unroll
      for (int i = 0; i < 4; ++i)
        #pragma unroll
        for (int j = 0; j < 8; ++j) acc[i][j] = fmaf(a_[i], b_[j], acc[i][j]);
    }
  }
  #pragma unroll
  for (int i = 0; i < 4; ++i){
    const int m = m0 + tm*4 + i;
    const int b = m >> 11, s = m & 2047;
    #pragma unroll
    for (int j = 0; j < 8; ++j){
      const int oc = tn*8 + j;
      float v = acc[i][j] + lb[oc];
      v = (v >= 0.f) ? v : 0.1f*v;
      out[((size_t)b*NOC + oc)*NS + s] = v;
    }
  }
}

// ---------------- host ----------------
extern "C" void kernel_launch(void* const* d_in, const int* in_sizes, int n_in,
                              void* d_out, int out_size, void* d_ws, size_t ws_size,
                              hipStream_t stream){
  const float* xyz = (const float*)d_in[0];
  const float* pts = (const float*)d_in[1];
  const float* w1  = (const float*)d_in[2];
  const float* b1  = (const float*)d_in[3];
  const float* w2  = (const float*)d_in[4];
  const float* b2  = (const float*)d_in[5];
  const float* w3  = (const float*)d_in[6];
  const float* b3  = (const float*)d_in[7];
  const float* lw  = (const float*)d_in[8];
  const float* lb  = (const float*)d_in[9];
  float* out = (float*)d_out;
  float* ws  = (float*)d_ws;
  // ws layout (floats): needs ~86.8 MB total
  float* pk   = ws;                    // 4,194,304  : packed [B][N][64]
  float* nxyz = ws + 4194304;          //    49,152  : new_xyz [B][S][3]
  int*   knn_ = (int*)(ws + 4259840);  //   524,288  : knn idx [B][S][32]
  float* lwT  = ws + 4784128;          //   131,072  : lw transposed [1024][128]
  float* agg  = ws + 4915200;          // 16,777,216 : agg [B*S][1024]
  // fps_idx output convention: float (out_size==2162688) vs raw int64 (2179072)
  const int idx_mode = (out_size >= 2179072) ? 1 : 0;

  pack_kernel<<<dim3(256), dim3(256), 0, stream>>>(xyz, pts, pk);
  transpose_lw_kernel<<<dim3(128), dim3(256), 0, stream>>>(lw, lwT);
  fps_kernel<<<dim3(NBATCH), dim3(1024), 0, stream>>>(xyz, nxyz, out, idx_mode);
  knn_kernel<<<dim3(NBATCH*NS), dim3(256), 0, stream>>>(xyz, nxyz, knn_);
  group_agg_kernel<<<dim3(2048), dim3(256), 0, stream>>>(pk, nxyz, knn_,
      w1, b1, w2, b2, w3, b3, agg);
  out_gemm_kernel<<<dim3(256), dim3(256), 0, stream>>>(agg, lwT, lb, out + NBATCH*3*NS);
}

// Round 15
// 3318.530 us; speedup vs baseline: 1.2708x; 1.0483x over previous
//
#include <hip/hip_runtime.h>
#include <cstdint>

// Problem constants (from reference)
constexpr int NPTS = 8192;     // N
constexpr int NBATCH = 8;      // B
constexpr int NS = 2048;       // NPOINT
constexpr int NK = 32;         // K neighbors
constexpr int NCH = 64;        // 3 + D(61)
constexpr int NW = 16;         // weightnet out
constexpr int NOC = 128;       // out channels
constexpr int NCAND = 512;     // knn threshold-bin candidate cap
constexpr long long IDX_OUT_OFF = (long long)NBATCH*3*NS + (long long)NBATCH*NOC*NS; // 2146304

// ---------------- K0a: pack xyz+points -> pk[b][n][64] (point-major) ----------------
__global__ __launch_bounds__(256) void pack_kernel(const float* __restrict__ xyz,
    const float* __restrict__ pts, float* __restrict__ pk){
  __shared__ float tile[64][256];
  const int blk = blockIdx.x; const int b = blk >> 5; const int n0 = (blk & 31) * 256;
  const int t = threadIdx.x;
  for (int r = 0; r < 64; ++r) {
    const float* src = (r < 3) ? (xyz + ((size_t)b*3 + r)*NPTS)
                               : (pts + ((size_t)b*61 + (r-3))*NPTS);
    tile[r][t] = src[n0 + t];
  }
  __syncthreads();
  float* dst = pk + ((size_t)b*NPTS + n0 + t)*64;
  #pragma unroll
  for (int c = 0; c < 16; ++c) {
    float4 v = make_float4(tile[4*c][t], tile[4*c+1][t], tile[4*c+2][t], tile[4*c+3][t]);
    *(float4*)(dst + 4*c) = v;
  }
}

// ---------------- K0b: transpose lw[128][1024] -> lwT[1024][128] ----------------
__global__ __launch_bounds__(256) void transpose_lw_kernel(const float* __restrict__ lw,
    float* __restrict__ lwT){
  __shared__ float tile[32][33];
  const int bx = blockIdx.x & 31;   // k-tile (32)
  const int by = blockIdx.x >> 5;   // oc-tile (4)
  const int tx = threadIdx.x & 31, ty0 = threadIdx.x >> 5;
  #pragma unroll
  for (int r = 0; r < 4; ++r){
    int ty = ty0 + r*8;
    tile[ty][tx] = lw[(size_t)(by*32+ty)*1024 + bx*32 + tx];
  }
  __syncthreads();
  #pragma unroll
  for (int r = 0; r < 4; ++r){
    int ty = ty0 + r*8;
    lwT[(size_t)(bx*32+ty)*128 + by*32 + tx] = tile[tx][ty];
  }
}

// ---------------- K1: furthest point sampling (1 block per batch) ----------------
// r12 post-mortem: 16 waves paid the u64 reduce 4x per SIMD (VALU-issue-bound,
// 63% busy on active CUs). Now 256 threads = 1 wave/SIMD, 32 pts/thread: same
// distance-update work per SIMD (768 cyc floor), reduce issued once not 4x.
// Numerics bit-identical to verified kernels: contract(off), ((dx2+dy2)+dz2),
// fminf vs 1e10, per-thread strict > over ascending j (ascending global idx),
// u64 key (f32bits<<32)|~idx -> global smallest-index-on-max = jnp.argmax.
__global__ __launch_bounds__(256) void fps_kernel(const float* __restrict__ xyz,
    float* __restrict__ newxyz /*[B][S][3]*/, float* __restrict__ out, int idx_mode){
#pragma clang fp contract(off)
  const int b = blockIdx.x, t = threadIdx.x;
  __shared__ float4 spt[NPTS];               // 128 KB: (x,y,z,0) per point
  __shared__ int shist[NS];                  // 8 KB: chosen index per step
  __shared__ unsigned long long slot[2];
  const float* xb = xyz + (size_t)b*3*NPTS;
  float px[32], py[32], pz[32], md[32];
  #pragma unroll
  for (int j = 0; j < 32; ++j){
    int n = t + j*256;
    float x = xb[n], y = xb[NPTS+n], z = xb[2*NPTS+n];
    px[j]=x; py[j]=y; pz[j]=z;
    spt[n] = make_float4(x, y, z, 0.f);
    md[j] = 1e10f;
  }
  if (t == 0){ slot[0] = 0ull; slot[1] = 0ull; }
  __syncthreads();
  int last = 0;
  float4 c0 = spt[0];
  float qx = c0.x, qy = c0.y, qz = c0.z;
  for (int s = 0; s < NS-1; ++s){
    if (t == 0) shist[s] = last;
    float bv = -1.0f; int bi = 0;
    #pragma unroll
    for (int j = 0; j < 32; ++j){
      float dx=px[j]-qx, dy=py[j]-qy, dz=pz[j]-qz;
      float d = (dx*dx + dy*dy) + dz*dz;
      float m = fminf(md[j], d);
      md[j] = m;
      if (m > bv){ bv = m; bi = t + j*256; }   // ascending j => smallest idx on tie
    }
    unsigned long long pk =
        ((unsigned long long)__float_as_uint(bv) << 32) | (unsigned)(~bi);
    #pragma unroll
    for (int off = 32; off; off >>= 1){
      unsigned long long o2 = __shfl_xor(pk, off);
      if (o2 > pk) pk = o2;
    }
    if ((t & 63) == 0) atomicMax(&slot[s & 1], pk);
    __syncthreads();                            // B1: all atomicMaxes visible
    unsigned long long win = slot[s & 1];
    last = (int)(~(unsigned)win);
    float4 cc = spt[last];                      // broadcast b128
    qx = cc.x; qy = cc.y; qz = cc.z;
    if (t == 0) slot[(s + 1) & 1] = 0ull;
    __syncthreads();                            // B2: zero visible before next use
  }
  if (t == 0) shist[NS-1] = last;
  __syncthreads();
  // epilogue: write all outputs from shist/spt (8 rounds of 256 threads)
  #pragma unroll
  for (int r = 0; r < 8; ++r){
    int s = t + r*256;
    int idx = shist[s];
    float4 c = spt[idx];
    size_t o = ((size_t)b*NS+s)*3;
    newxyz[o]=c.x; newxyz[o+1]=c.y; newxyz[o+2]=c.z;
    out[(size_t)b*3*NS + s]        = c.x;
    out[(size_t)b*3*NS + NS + s]   = c.y;
    out[(size_t)b*3*NS + 2*NS + s] = c.z;
    if (idx_mode == 0) out[IDX_OUT_OFF + (size_t)b*NS + s] = (float)idx;
    else ((long long*)(out + IDX_OUT_OFF))[(size_t)b*NS + s] = (long long)idx;
  }
}

// ---------------- K2: KNN via per-query histogram select (1 block per query) ----------------
// Distance formula mimics reference: d = (|q|^2 + |p|^2) - 2*((qx*px+qy*py)+qz*pz),
// mul/add (no fma contraction) to track XLA's emission; can be slightly negative.
__global__ __launch_bounds__(256) void knn_kernel(const float* __restrict__ xyz,
    const float* __restrict__ nxyz /*[B][S][3]*/, int* __restrict__ knn_out){
#pragma clang fp contract(off)
  const int q = blockIdx.x; const int b = q >> 11;
  const int t = threadIdx.x;
  __shared__ float dist[NPTS];
  __shared__ unsigned hist[4096];
  __shared__ unsigned scnt[256];
  __shared__ int s_bin, s_below;
  __shared__ unsigned cnt_sure, cnt_cand;
  __shared__ float cd[NCAND]; __shared__ int cidx[NCAND];
  const float* xb = xyz + (size_t)b*3*NPTS;
  const float qx = nxyz[(size_t)q*3+0], qy = nxyz[(size_t)q*3+1], qz = nxyz[(size_t)q*3+2];
  const float sqq = (qx*qx + qy*qy) + qz*qz;
  #pragma unroll
  for (int j = 0; j < 16; ++j) hist[t + 256*j] = 0u;
  if (t == 0){ cnt_sure = 0u; cnt_cand = 0u; }
  __syncthreads();
  #pragma unroll
  for (int j = 0; j < 32; ++j){
    int n = t + 256*j;
    float x = xb[n], y = xb[NPTS+n], z = xb[2*NPTS+n];
    float sqn = (x*x + y*y) + z*z;
    float dot = (qx*x + qy*y) + qz*z;
    float d = (sqq + sqn) - 2.0f*dot;
    dist[n] = d;
    unsigned ub = __float_as_uint(d);
    ub = (ub & 0x80000000u) ? ~ub : (ub | 0x80000000u);  // monotonic float->uint
    atomicAdd(&hist[ub >> 20], 1u);
  }
  __syncthreads();
  unsigned ps = 0;
  #pragma unroll
  for (int j = 0; j < 16; ++j) ps += hist[t*16 + j];
  scnt[t] = ps;
  __syncthreads();
  if (t < 64){
    unsigned v4 = scnt[4*t] + scnt[4*t+1] + scnt[4*t+2] + scnt[4*t+3];
    unsigned cum = v4;
    #pragma unroll
    for (int o = 1; o < 64; o <<= 1){
      unsigned p = __shfl_up(cum, o);
      if (t >= o) cum += p;
    }
    unsigned long long mask = __ballot(cum >= 32u);
    int L = __ffsll(mask) - 1;
    if (t == L){
      unsigned below = cum - v4;
      int bin = -1;
      for (int i = 4*L; i < 4*L+4; ++i){
        if (below + scnt[i] >= 32u){
          for (int k = 16*i;; ++k){
            if (below + hist[k] >= 32u){ bin = k; break; }
            below += hist[k];
          }
          break;
        }
        below += scnt[i];
      }
      s_bin = bin; s_below = (int)below;
    }
  }
  __syncthreads();
  const int Bb = s_bin, below = s_below, m = 32 - below;
  int* outp = knn_out + (size_t)q*NK;
  #pragma unroll
  for (int j = 0; j < 32; ++j){
    int n = t + 256*j;
    unsigned ub = __float_as_uint(dist[n]);
    ub = (ub & 0x80000000u) ? ~ub : (ub | 0x80000000u);
    unsigned bin = ub >> 20;
    if (bin < (unsigned)Bb){
      unsigned p = atomicAdd(&cnt_sure, 1u);
      outp[p] = n;
    } else if (bin == (unsigned)Bb){
      unsigned p = atomicAdd(&cnt_cand, 1u);
      if (p < (unsigned)NCAND){ cd[p] = dist[n]; cidx[p] = n; }
    }
  }
  __syncthreads();
  int c = (int)cnt_cand; if (c > NCAND) c = NCAND;
  if (t < c){
    float myd = cd[t]; int myi = cidx[t];
    int r = 0;
    for (int j = 0; j < c; ++j){
      float dj = cd[j]; int ij = cidx[j];
      if (dj < myd || (dj == myd && ij < myi)) r++;
    }
    if (r < m) outp[below + r] = myi;
  }
  // candidate entries 256..c-1 (c can exceed blockDim)
  for (int base = 256; base < c; base += 256){
    int idx = base + t;
    if (idx < c){
      float myd = cd[idx]; int myi = cidx[idx];
      int r = 0;
      for (int j = 0; j < c; ++j){
        float dj = cd[j]; int ij = cidx[j];
        if (dj < myd || (dj == myd && ij < myi)) r++;
      }
      if (r < m) outp[below + r] = myi;
    }
  }
}

// ---------------- K3: gather + WeightNet + aggregate -> agg[q][1024] ----------------
__global__ __launch_bounds__(256) void group_agg_kernel(const float* __restrict__ pk,
    const float* __restrict__ nxyz, const int* __restrict__ knn_in,
    const float* __restrict__ w1, const float* __restrict__ b1,
    const float* __restrict__ w2, const float* __restrict__ b2,
    const float* __restrict__ w3, const float* __restrict__ b3,
    float* __restrict__ agg){
  const int t = threadIdx.x;
  __shared__ float np[32][65];
  __shared__ float h1[32][9];
  __shared__ float h2[32][9];
  __shared__ float wt[32][17];
  __shared__ int sidx[32];
  const int kg = t >> 3, c0 = (t & 7) * 8;   // gather: (k, 8 channels)
  const int ko = t >> 3, oo = t & 7;         // layers 1/2: (k, out)
  const int kw = t >> 4, wo = t & 15;        // layer 3: (k, w) ×2
  const int ca = t >> 2, wa = (t & 3) * 4;   // agg: (c, 4 w)
  for (int qq = 0; qq < 8; ++qq){
    const int q = blockIdx.x*8 + qq;
    const int b = q >> 11;
    if (t < 32) sidx[t] = knn_in[(size_t)q*NK + t];
    __syncthreads();
    const float qx = nxyz[(size_t)q*3+0], qy = nxyz[(size_t)q*3+1], qz = nxyz[(size_t)q*3+2];
    {
      const float* src = pk + ((size_t)b*NPTS + sidx[kg])*64 + c0;
      float4 v0 = *(const float4*)src;
      float4 v1 = *(const float4*)(src + 4);
      if (c0 == 0){ v0.x -= qx; v0.y -= qy; v0.z -= qz; }
      np[kg][c0+0]=v0.x; np[kg][c0+1]=v0.y; np[kg][c0+2]=v0.z; np[kg][c0+3]=v0.w;
      np[kg][c0+4]=v1.x; np[kg][c0+5]=v1.y; np[kg][c0+6]=v1.z; np[kg][c0+7]=v1.w;
    }
    __syncthreads();
    h1[ko][oo] = fmaxf(w1[oo*3+0]*np[ko][0] + w1[oo*3+1]*np[ko][1] + w1[oo*3+2]*np[ko][2] + b1[oo], 0.f);
    __syncthreads();
    {
      float a = b2[oo];
      #pragma unroll
      for (int j = 0; j < 8; ++j) a = fmaf(w2[oo*8+j], h1[ko][j], a);
      h2[ko][oo] = fmaxf(a, 0.f);
    }
    __syncthreads();
    {
      float a = b3[wo], a2 = b3[wo];
      #pragma unroll
      for (int j = 0; j < 8; ++j){
        a  = fmaf(w3[wo*8+j], h2[kw][j],    a);
        a2 = fmaf(w3[wo*8+j], h2[kw+16][j], a2);
      }
      wt[kw][wo]    = fmaxf(a, 0.f);
      wt[kw+16][wo] = fmaxf(a2, 0.f);
    }
    __syncthreads();
    {
      float a0=0.f, a1=0.f, a2=0.f, a3=0.f;
      #pragma unroll
      for (int k = 0; k < 32; ++k){
        float a = np[k][ca];
        a0 = fmaf(a, wt[k][wa+0], a0);
        a1 = fmaf(a, wt[k][wa+1], a1);
        a2 = fmaf(a, wt[k][wa+2], a2);
        a3 = fmaf(a, wt[k][wa+3], a3);
      }
      *(float4*)(agg + (size_t)q*1024 + ca*16 + wa) = make_float4(a0,a1,a2,a3);
    }
    __syncthreads();
  }
}

// ---------------- K4: out = leaky(agg @ lwT + lb), transposed write ----------------
__global__ __launch_bounds__(256) void out_gemm_kernel(const float* __restrict__ agg,
    const float* __restrict__ lwT, const float* __restrict__ lb, float* __restrict__ out){
  __shared__ float At[32][68];   // [k][m], padded
  const int t = threadIdx.x;
  const int m0 = blockIdx.x * 64;
  const int tm = t >> 4, tn = t & 15;      // thread tile: 4 m × 8 oc
  const int sr = t >> 2, sq = (t & 3) * 2; // staging: row, float4-quad pair
  float acc[4][8];
  #pragma unroll
  for (int i = 0; i < 4; ++i)
    #pragma unroll
    for (int j = 0; j < 8; ++j) acc[i][j] = 0.f;
  for (int kt = 0; kt < 32; ++kt){
    const float4* srcA = (const float4*)(agg + ((size_t)(m0+sr))*1024 + (size_t)kt*32);
    float4 a0 = srcA[sq], a1 = srcA[sq+1];
    __syncthreads();
    At[sq*4+0][sr]=a0.x; At[sq*4+1][sr]=a0.y; At[sq*4+2][sr]=a0.z; At[sq*4+3][sr]=a0.w;
    At[sq*4+4][sr]=a1.x; At[sq*4+5][sr]=a1.y; At[sq*4+6][sr]=a1.z; At[sq*4+7][sr]=a1.w;
    __syncthreads();
    const float* bbase = lwT + (size_t)kt*32*128 + tn*8;
    #pragma unroll
    for (int k = 0; k < 32; ++k){
      float4 av = *(const float4*)&At[k][tm*4];
      float4 b0 = *(const float4*)(bbase + k*128);
      float4 b1 = *(const float4*)(bbase + k*128 + 4);
      float a_[4] = {av.x, av.y, av.z, av.w};
      float b_[8] = {b0.x,b0.y,b0.z,b0.w,b1.x,b1.y,b1.z,b1.w};
      #pragma unroll
      for (int i = 0; i < 4; ++i)
        #pragma unroll
        for (int j = 0; j < 8; ++j) acc[i][j] = fmaf(a_[i], b_[j], acc[i][j]);
    }
  }
  #pragma unroll
  for (int i = 0; i < 4; ++i){
    const int m = m0 + tm*4 + i;
    const int b = m >> 11, s = m & 2047;
    #pragma unroll
    for (int j = 0; j < 8; ++j){
      const int oc = tn*8 + j;
      float v = acc[i][j] + lb[oc];
      v = (v >= 0.f) ? v : 0.1f*v;
      out[((size_t)b*NOC + oc)*NS + s] = v;
    }
  }
}

// ---------------- host ----------------
extern "C" void kernel_launch(void* const* d_in, const int* in_sizes, int n_in,
                              void* d_out, int out_size, void* d_ws, size_t ws_size,
                              hipStream_t stream){
  const float* xyz = (const float*)d_in[0];
  const float* pts = (const float*)d_in[1];
  const float* w1  = (const float*)d_in[2];
  const float* b1  = (const float*)d_in[3];
  const float* w2  = (const float*)d_in[4];
  const float* b2  = (const float*)d_in[5];
  const float* w3  = (const float*)d_in[6];
  const float* b3  = (const float*)d_in[7];
  const float* lw  = (const float*)d_in[8];
  const float* lb  = (const float*)d_in[9];
  float* out = (float*)d_out;
  float* ws  = (float*)d_ws;
  // ws layout (floats): needs ~86.8 MB total
  float* pk   = ws;                    // 4,194,304  : packed [B][N][64]
  float* nxyz = ws + 4194304;          //    49,152  : new_xyz [B][S][3]
  int*   knn_ = (int*)(ws + 4259840);  //   524,288  : knn idx [B][S][32]
  float* lwT  = ws + 4784128;          //   131,072  : lw transposed [1024][128]
  float* agg  = ws + 4915200;          // 16,777,216 : agg [B*S][1024]
  // fps_idx output convention: float (out_size==2162688) vs raw int64 (2179072)
  const int idx_mode = (out_size >= 2179072) ? 1 : 0;

  pack_kernel<<<dim3(256), dim3(256), 0, stream>>>(xyz, pts, pk);
  transpose_lw_kernel<<<dim3(128), dim3(256), 0, stream>>>(lw, lwT);
  fps_kernel<<<dim3(NBATCH), dim3(256), 0, stream>>>(xyz, nxyz, out, idx_mode);
  knn_kernel<<<dim3(NBATCH*NS), dim3(256), 0, stream>>>(xyz, nxyz, knn_);
  group_agg_kernel<<<dim3(2048), dim3(256), 0, stream>>>(pk, nxyz, knn_,
      w1, b1, w2, b2, w3, b3, agg);
  out_gemm_kernel<<<dim3(256), dim3(256), 0, stream>>>(agg, lwT, lb, out + NBATCH*3*NS);
}